// Round 1
// baseline (1259.240 us; speedup 1.0000x reference)
//
#include <hip/hip_runtime.h>
#include <hip/hip_bf16.h>

#define EPSF 1e-5f

static constexpr int NGRAPH = 64;

__device__ __forceinline__ void gAtomicAdd(float* p, float v) {
  unsafeAtomicAdd(p, v);  // native global_atomic_add_f32 on gfx950
}

// ---------- BN0 stats over x [N,4]: sum[4], sumsq[4] -> stats[8] ----------
__global__ void k_bnstats(const float4* __restrict__ x, int N,
                          float* __restrict__ stats) {
  float s[4] = {0, 0, 0, 0}, q[4] = {0, 0, 0, 0};
  for (int i = blockIdx.x * blockDim.x + threadIdx.x; i < N;
       i += gridDim.x * blockDim.x) {
    float4 v = x[i];
    s[0] += v.x; q[0] += v.x * v.x;
    s[1] += v.y; q[1] += v.y * v.y;
    s[2] += v.z; q[2] += v.z * v.z;
    s[3] += v.w; q[3] += v.w * v.w;
  }
#pragma unroll
  for (int o = 32; o > 0; o >>= 1) {
#pragma unroll
    for (int k = 0; k < 4; k++) {
      s[k] += __shfl_down(s[k], o);
      q[k] += __shfl_down(q[k], o);
    }
  }
  if ((threadIdx.x & 63) == 0) {
#pragma unroll
    for (int k = 0; k < 4; k++) {
      gAtomicAdd(&stats[k], s[k]);
      gAtomicAdd(&stats[4 + k], q[k]);
    }
  }
}

// ---------- degree count: degcnt[dst] += 1 ----------
__global__ void k_deg(const int* __restrict__ ei, int E,
                      float* __restrict__ degcnt) {
  for (int e = blockIdx.x * blockDim.x + threadIdx.x; e < E;
       e += gridDim.x * blockDim.x) {
    int d = ei[E + e];
    gAtomicAdd(&degcnt[d], 1.0f);
  }
}

// ---------- dinv = 1/sqrt(deg), invdeg = 1/deg (deg = count + 1 self loop) --
__global__ void k_dinv(const float* __restrict__ degcnt, int N,
                       float* __restrict__ dinv, float* __restrict__ invdeg) {
  int i = blockIdx.x * blockDim.x + threadIdx.x;
  if (i < N) {
    float d = degcnt[i] + 1.0f;
    dinv[i] = 1.0f / sqrtf(d);
    invdeg[i] = 1.0f / d;
  }
}

__device__ __forceinline__ void bn0_coefs(const float* __restrict__ stats,
                                          const float* __restrict__ g,
                                          const float* __restrict__ b,
                                          float Ninv, float* sc, float* sh) {
#pragma unroll
  for (int k = 0; k < 4; k++) {
    float mu = stats[k] * Ninv;
    float var = stats[4 + k] * Ninv - mu * mu;
    var = var < 0.f ? 0.f : var;
    float s = g[k] / sqrtf(var + EPSF);
    sc[k] = s;
    sh[k] = b[k] - mu * s;
  }
}

// ---------- edge pass A: acc[dst] += dinv[src] * xbn[src]  (4 floats) ------
__global__ void k_edgeA(const int* __restrict__ ei, int E,
                        const float4* __restrict__ x,
                        const float* __restrict__ dinv,
                        const float* __restrict__ stats,
                        const float* __restrict__ bn0g,
                        const float* __restrict__ bn0b, float Ninv,
                        float* __restrict__ acc) {
  float sc[4], sh[4];
  bn0_coefs(stats, bn0g, bn0b, Ninv, sc, sh);
  for (int e = blockIdx.x * blockDim.x + threadIdx.x; e < E;
       e += gridDim.x * blockDim.x) {
    int s = ei[e];
    int d = ei[E + e];
    float w = dinv[s];
    float4 xv = x[s];
    float* a = acc + 4 * d;
    gAtomicAdd(a + 0, w * (xv.x * sc[0] + sh[0]));
    gAtomicAdd(a + 1, w * (xv.y * sc[1] + sh[1]));
    gAtomicAdd(a + 2, w * (xv.z * sc[2] + sh[2]));
    gAtomicAdd(a + 3, w * (xv.w * sc[3] + sh[3]));
  }
}

// ---------- node pass: pre1 = dinv*acc + invdeg*xbn; node-side U/S/cnt -----
__global__ void k_pre1(const float4* __restrict__ x,
                       const float4* __restrict__ acc,
                       const float* __restrict__ dinv,
                       const float* __restrict__ invdeg,
                       const int* __restrict__ batch, int N,
                       const float* __restrict__ stats,
                       const float* __restrict__ bn0g,
                       const float* __restrict__ bn0b, float Ninv,
                       float4* __restrict__ pre1, float* __restrict__ U,
                       float* __restrict__ S, float* __restrict__ cnt) {
  __shared__ float lac[NGRAPH * 7];  // slots 0..3: U, 4: S, 5: cnt
  for (int t = threadIdx.x; t < NGRAPH * 7; t += blockDim.x) lac[t] = 0.f;
  float sc[4], sh[4];
  bn0_coefs(stats, bn0g, bn0b, Ninv, sc, sh);
  __syncthreads();
  for (int i = blockIdx.x * blockDim.x + threadIdx.x; i < N;
       i += gridDim.x * blockDim.x) {
    float4 xv = x[i];
    float4 a = acc[i];
    float dv = dinv[i], idg = invdeg[i];
    float4 p;
    p.x = dv * a.x + idg * (xv.x * sc[0] + sh[0]);
    p.y = dv * a.y + idg * (xv.y * sc[1] + sh[1]);
    p.z = dv * a.z + idg * (xv.z * sc[2] + sh[2]);
    p.w = dv * a.w + idg * (xv.w * sc[3] + sh[3]);
    pre1[i] = p;
    int g = batch[i] * 7;
    atomicAdd(&lac[g + 0], p.x * idg);
    atomicAdd(&lac[g + 1], p.y * idg);
    atomicAdd(&lac[g + 2], p.z * idg);
    atomicAdd(&lac[g + 3], p.w * idg);
    atomicAdd(&lac[g + 4], idg);
    atomicAdd(&lac[g + 5], 1.0f);
  }
  __syncthreads();
  for (int t = threadIdx.x; t < NGRAPH; t += blockDim.x) {
    gAtomicAdd(&U[t * 4 + 0], lac[t * 7 + 0]);
    gAtomicAdd(&U[t * 4 + 1], lac[t * 7 + 1]);
    gAtomicAdd(&U[t * 4 + 2], lac[t * 7 + 2]);
    gAtomicAdd(&U[t * 4 + 3], lac[t * 7 + 3]);
    gAtomicAdd(&S[t], lac[t * 7 + 4]);
    gAtomicAdd(&cnt[t], lac[t * 7 + 5]);
  }
}

// ---------- edge pass B: per-graph U += w*pre1[src], S += w ----------------
__global__ void k_edgeB(const int* __restrict__ ei, int E,
                        const float4* __restrict__ pre1,
                        const float* __restrict__ dinv,
                        const int* __restrict__ batch, float* __restrict__ U,
                        float* __restrict__ S) {
  __shared__ float lac[NGRAPH * 5];  // stride 5 -> coprime with 32 banks
  for (int t = threadIdx.x; t < NGRAPH * 5; t += blockDim.x) lac[t] = 0.f;
  __syncthreads();
  for (int e = blockIdx.x * blockDim.x + threadIdx.x; e < E;
       e += gridDim.x * blockDim.x) {
    int s = ei[e];
    int d = ei[E + e];
    float w = dinv[s] * dinv[d];
    int g = batch[d] * 5;
    float4 p = pre1[s];
    atomicAdd(&lac[g + 0], w * p.x);
    atomicAdd(&lac[g + 1], w * p.y);
    atomicAdd(&lac[g + 2], w * p.z);
    atomicAdd(&lac[g + 3], w * p.w);
    atomicAdd(&lac[g + 4], w);
  }
  __syncthreads();
  for (int t = threadIdx.x; t < NGRAPH; t += blockDim.x) {
    gAtomicAdd(&U[t * 4 + 0], lac[t * 5 + 0]);
    gAtomicAdd(&U[t * 4 + 1], lac[t * 5 + 1]);
    gAtomicAdd(&U[t * 4 + 2], lac[t * 5 + 2]);
    gAtomicAdd(&U[t * 4 + 3], lac[t * 5 + 3]);
    gAtomicAdd(&S[t], lac[t * 5 + 4]);
  }
}

// ---------- epilogue: g_raw = U@(W0W1)+S*(b0W1)+cnt*b1 -> BN -> MLP --------
__global__ void k_final(const float* __restrict__ U, const float* __restrict__ S,
                        const float* __restrict__ cnt,
                        const float* __restrict__ W0, const float* __restrict__ b0,
                        const float* __restrict__ W1, const float* __restrict__ b1,
                        const float* __restrict__ bn1g,
                        const float* __restrict__ bn1b,
                        const float* __restrict__ l0W, const float* __restrict__ l0b,
                        const float* __restrict__ l1W, const float* __restrict__ l1b,
                        const float* __restrict__ oW, const float* __restrict__ ob,
                        float* __restrict__ out) {
  __shared__ float sW01[4 * 64];
  __shared__ float sb01[64];
  __shared__ float sA[64 * 64];
  __shared__ float sB[64 * 64];
  __shared__ float sSc[64], sSh[64];
  int t = threadIdx.x;
  {
    int k = t >> 6, f = t & 63;
    float a = 0.f;
    for (int j = 0; j < 64; j++) a += W0[k * 64 + j] * W1[j * 64 + f];
    sW01[k * 64 + f] = a;
  }
  if (t < 64) {
    float a = 0.f;
    for (int j = 0; j < 64; j++) a += b0[j] * W1[j * 64 + t];
    sb01[t] = a;
  }
  __syncthreads();
  for (int idx = t; idx < 4096; idx += 256) {
    int G = idx >> 6, f = idx & 63;
    float v = cnt[G] * b1[f] + S[G] * sb01[f];
    v += U[G * 4 + 0] * sW01[0 * 64 + f];
    v += U[G * 4 + 1] * sW01[1 * 64 + f];
    v += U[G * 4 + 2] * sW01[2 * 64 + f];
    v += U[G * 4 + 3] * sW01[3 * 64 + f];
    sA[idx] = v;
  }
  __syncthreads();
  if (t < 64) {
    float mu = 0.f;
    for (int G = 0; G < 64; G++) mu += sA[G * 64 + t];
    mu *= (1.0f / 64.0f);
    float var = 0.f;
    for (int G = 0; G < 64; G++) {
      float d = sA[G * 64 + t] - mu;
      var += d * d;
    }
    var *= (1.0f / 64.0f);
    float s = bn1g[t] / sqrtf(var + EPSF);
    sSc[t] = s;
    sSh[t] = bn1b[t] - mu * s;
  }
  __syncthreads();
  for (int idx = t; idx < 4096; idx += 256) {
    int f = idx & 63;
    sA[idx] = sA[idx] * sSc[f] + sSh[f];
  }
  __syncthreads();
  for (int idx = t; idx < 4096; idx += 256) {
    int G = idx >> 6, f = idx & 63;
    float v = l0b[f];
    for (int j = 0; j < 64; j++) v += sA[G * 64 + j] * l0W[j * 64 + f];
    sB[idx] = v;
  }
  __syncthreads();
  for (int idx = t; idx < 4096; idx += 256) {
    int G = idx >> 6, f = idx & 63;
    float v = l1b[f];
    for (int j = 0; j < 64; j++) v += sB[G * 64 + j] * l1W[j * 64 + f];
    sA[idx] = v;
  }
  __syncthreads();
  if (t < 64) {
    float v = ob[0];
    for (int j = 0; j < 64; j++) v += sA[t * 64 + j] * oW[j];
    out[t] = v;
  }
}

extern "C" void kernel_launch(void* const* d_in, const int* in_sizes, int n_in,
                              void* d_out, int out_size, void* d_ws,
                              size_t ws_size, hipStream_t stream) {
  const float* x = (const float*)d_in[0];
  const int* ei = (const int*)d_in[1];
  const int* batch = (const int*)d_in[2];
  const float* bn0g = (const float*)d_in[3];
  const float* bn0b = (const float*)d_in[4];
  const float* W0 = (const float*)d_in[5];
  const float* b0 = (const float*)d_in[6];
  const float* W1 = (const float*)d_in[7];
  const float* b1 = (const float*)d_in[8];
  const float* bn1g = (const float*)d_in[9];
  const float* bn1b = (const float*)d_in[10];
  const float* l0W = (const float*)d_in[11];
  const float* l0b = (const float*)d_in[12];
  const float* l1W = (const float*)d_in[13];
  const float* l1b = (const float*)d_in[14];
  const float* oW = (const float*)d_in[15];
  const float* ob = (const float*)d_in[16];

  const int N = in_sizes[0] / 4;
  const int E = in_sizes[1] / 2;

  float* ws = (float*)d_ws;
  size_t off = 0;
  auto alloc = [&](size_t nf) {
    float* p = ws + off;
    off += (nf + 3) & ~size_t(3);  // keep 16B alignment for float4 regions
    return p;
  };
  float* degcnt = alloc((size_t)N);       // zeroed
  float* acc = alloc(4 * (size_t)N);      // zeroed
  float* stats = alloc(8);                // zeroed
  float* U = alloc(NGRAPH * 4);           // zeroed
  float* S = alloc(NGRAPH);               // zeroed
  float* cnt = alloc(NGRAPH);             // zeroed
  const size_t zero_floats = off;
  float* dinv = alloc((size_t)N);
  float* invdeg = alloc((size_t)N);
  float* pre1 = alloc(4 * (size_t)N);

  hipMemsetAsync(d_ws, 0, zero_floats * sizeof(float), stream);

  const float Ninv = 1.0f / (float)N;
  k_bnstats<<<256, 256, 0, stream>>>((const float4*)x, N, stats);
  k_deg<<<1024, 256, 0, stream>>>(ei, E, degcnt);
  k_dinv<<<(N + 255) / 256, 256, 0, stream>>>(degcnt, N, dinv, invdeg);
  k_edgeA<<<2048, 256, 0, stream>>>(ei, E, (const float4*)x, dinv, stats, bn0g,
                                    bn0b, Ninv, acc);
  k_pre1<<<(N + 255) / 256, 256, 0, stream>>>(
      (const float4*)x, (const float4*)acc, dinv, invdeg, batch, N, stats,
      bn0g, bn0b, Ninv, (float4*)pre1, U, S, cnt);
  k_edgeB<<<1024, 256, 0, stream>>>(ei, E, (const float4*)pre1, dinv, batch, U,
                                    S);
  k_final<<<1, 256, 0, stream>>>(U, S, cnt, W0, b0, W1, b1, bn1g, bn1b, l0W,
                                 l0b, l1W, l1b, oW, ob, (float*)d_out);
}

// Round 2
// 851.951 us; speedup vs baseline: 1.4781x; 1.4781x over previous
//
#include <hip/hip_runtime.h>
#include <hip/hip_bf16.h>

#define EPSF 1e-5f

static constexpr int NGRAPH = 64;
static constexpr float QSCALE = 524288.f;   // 2^19
static constexpr float QBIAS = 16.f;        // per-edge positive bias
static constexpr int HB = 16384;            // histogram bins per range (64 KB LDS)
static constexpr int CHK = 32;              // edge chunks for histogram

__device__ __forceinline__ void gAtomicAdd(float* p, float v) {
  unsafeAtomicAdd(p, v);  // native global_atomic_add_f32 on gfx950
}

// ---------- BN0 stats over x [N,4]: sum[4], sumsq[4] -> stats[8] ----------
__global__ void k_bnstats(const float4* __restrict__ x, int N,
                          float* __restrict__ stats) {
  float s[4] = {0, 0, 0, 0}, q[4] = {0, 0, 0, 0};
  for (int i = blockIdx.x * blockDim.x + threadIdx.x; i < N;
       i += gridDim.x * blockDim.x) {
    float4 v = x[i];
    s[0] += v.x; q[0] += v.x * v.x;
    s[1] += v.y; q[1] += v.y * v.y;
    s[2] += v.z; q[2] += v.z * v.z;
    s[3] += v.w; q[3] += v.w * v.w;
  }
#pragma unroll
  for (int o = 32; o > 0; o >>= 1) {
#pragma unroll
    for (int k = 0; k < 4; k++) {
      s[k] += __shfl_down(s[k], o);
      q[k] += __shfl_down(q[k], o);
    }
  }
  if ((threadIdx.x & 63) == 0) {
#pragma unroll
    for (int k = 0; k < 4; k++) {
      gAtomicAdd(&stats[k], s[k]);
      gAtomicAdd(&stats[4 + k], q[k]);
    }
  }
}

// ---------- degree histogram: node-range partitioned, no global atomics ----
__global__ void k_hist(const int* __restrict__ ei, int E, int R, int chunk,
                       unsigned* __restrict__ part) {
  __shared__ unsigned h[HB];
  for (int t = threadIdx.x; t < HB; t += blockDim.x) h[t] = 0;
  __syncthreads();
  int r = blockIdx.x % R, c = blockIdx.x / R;
  int lo = c * chunk;
  int hi = min(E, lo + chunk);
  int base = r * HB;
  for (int e = lo + threadIdx.x; e < hi; e += blockDim.x) {
    unsigned rel = (unsigned)(ei[E + e] - base);
    if (rel < (unsigned)HB) atomicAdd(&h[rel], 1u);
  }
  __syncthreads();
  unsigned* out = part + (size_t)blockIdx.x * HB;
  for (int t = threadIdx.x; t < HB; t += blockDim.x) out[t] = h[t];
}

__global__ void k_degreduce(const unsigned* __restrict__ part, int N, int R,
                            unsigned* __restrict__ degcnt) {
  int v = blockIdx.x * blockDim.x + threadIdx.x;
  if (v >= N) return;
  int r = v / HB, off = v - r * HB;
  unsigned s = 0;
#pragma unroll 4
  for (int c = 0; c < CHK; c++) s += part[(size_t)(c * R + r) * HB + off];
  degcnt[v] = s;
}

// fallback if ws too small for partials
__global__ void k_degatomic(const int* __restrict__ ei, int E,
                            unsigned* __restrict__ degcnt) {
  for (int e = blockIdx.x * blockDim.x + threadIdx.x; e < E;
       e += gridDim.x * blockDim.x)
    atomicAdd(&degcnt[ei[E + e]], 1u);
}

__device__ __forceinline__ void bn0_coefs(const float* __restrict__ stats,
                                          const float* __restrict__ g,
                                          const float* __restrict__ b,
                                          float Ninv, float* sc, float* sh) {
#pragma unroll
  for (int k = 0; k < 4; k++) {
    float mu = stats[k] * Ninv;
    float var = stats[4 + k] * Ninv - mu * mu;
    var = var < 0.f ? 0.f : var;
    float s = g[k] / sqrtf(var + EPSF);
    sc[k] = s;
    sh[k] = b[k] - mu * s;
  }
}

// ---------- per-node prep: dinv, quantized z = dinv * xbn -------------------
__global__ void k_prep(const float4* __restrict__ x,
                       const unsigned* __restrict__ degcnt, int N,
                       const float* __restrict__ stats,
                       const float* __restrict__ bn0g,
                       const float* __restrict__ bn0b, float Ninv,
                       float* __restrict__ dinv, uint4* __restrict__ qz) {
  int i = blockIdx.x * blockDim.x + threadIdx.x;
  if (i >= N) return;
  float sc[4], sh[4];
  bn0_coefs(stats, bn0g, bn0b, Ninv, sc, sh);
  float dv = rsqrtf((float)degcnt[i] + 1.0f);
  dinv[i] = dv;
  float4 xv = x[i];
  float z0 = dv * (xv.x * sc[0] + sh[0]) + QBIAS;
  float z1 = dv * (xv.y * sc[1] + sh[1]) + QBIAS;
  float z2 = dv * (xv.z * sc[2] + sh[2]) + QBIAS;
  float z3 = dv * (xv.w * sc[3] + sh[3]) + QBIAS;
  const float hi = 2.f * QBIAS - 1e-3f;
  uint4 q;
  q.x = __float2uint_rn(fminf(fmaxf(z0, 0.f), hi) * QSCALE);
  q.y = __float2uint_rn(fminf(fmaxf(z1, 0.f), hi) * QSCALE);
  q.z = __float2uint_rn(fminf(fmaxf(z2, 0.f), hi) * QSCALE);
  q.w = __float2uint_rn(fminf(fmaxf(z3, 0.f), hi) * QSCALE);
  qz[i] = q;
}

// ---------- edge pass A: acc[dst] += qz[src], 2 packed u64 atomics ---------
__global__ void k_edgeA(const int* __restrict__ ei, int E,
                        const uint4* __restrict__ qz,
                        unsigned long long* __restrict__ acc) {
  for (int e = blockIdx.x * blockDim.x + threadIdx.x; e < E;
       e += gridDim.x * blockDim.x) {
    int s = ei[e];
    int d = ei[E + e];
    uint4 q = qz[s];
    unsigned long long p01 = (unsigned long long)q.x |
                             ((unsigned long long)q.y << 32);
    unsigned long long p23 = (unsigned long long)q.z |
                             ((unsigned long long)q.w << 32);
    atomicAdd(&acc[2 * (size_t)d + 0], p01);
    atomicAdd(&acc[2 * (size_t)d + 1], p23);
  }
}

// ---------- node pass: p2 = invdeg*(accsum+z); node-side U/S/cnt ----------
__global__ void k_pre1(const float4* __restrict__ x,
                       const ulonglong2* __restrict__ acc,
                       const unsigned* __restrict__ degcnt,
                       const float* __restrict__ dinv,
                       const int* __restrict__ batch, int N,
                       const float* __restrict__ stats,
                       const float* __restrict__ bn0g,
                       const float* __restrict__ bn0b, float Ninv,
                       float4* __restrict__ p2, float* __restrict__ U,
                       float* __restrict__ S, float* __restrict__ cnt) {
  __shared__ float lac[NGRAPH * 7];
  for (int t = threadIdx.x; t < NGRAPH * 7; t += blockDim.x) lac[t] = 0.f;
  float sc[4], sh[4];
  bn0_coefs(stats, bn0g, bn0b, Ninv, sc, sh);
  __syncthreads();
  const float inv_q = 1.0f / QSCALE;
  for (int i = blockIdx.x * blockDim.x + threadIdx.x; i < N;
       i += gridDim.x * blockDim.x) {
    ulonglong2 a = acc[i];
    long long bias = (long long)degcnt[i] << 23;  // m * 16 * 2^19
    float s0 = (float)((long long)(unsigned)a.x - bias) * inv_q;
    float s1 = (float)((long long)(a.x >> 32) - bias) * inv_q;
    float s2 = (float)((long long)(unsigned)a.y - bias) * inv_q;
    float s3 = (float)((long long)(a.y >> 32) - bias) * inv_q;
    float dv = dinv[i];
    float idg = dv * dv;
    float4 xv = x[i];
    float a0 = s0 + dv * (xv.x * sc[0] + sh[0]);
    float a1 = s1 + dv * (xv.y * sc[1] + sh[1]);
    float a2 = s2 + dv * (xv.z * sc[2] + sh[2]);
    float a3 = s3 + dv * (xv.w * sc[3] + sh[3]);
    float4 p;  // p2 = invdeg * (accsum + z) = dinv * pre1
    p.x = idg * a0; p.y = idg * a1; p.z = idg * a2; p.w = idg * a3;
    p2[i] = p;
    int g = batch[i] * 7;
    // node self-term of hop2: idg*pre1 = dinv*p2
    atomicAdd(&lac[g + 0], dv * p.x);
    atomicAdd(&lac[g + 1], dv * p.y);
    atomicAdd(&lac[g + 2], dv * p.z);
    atomicAdd(&lac[g + 3], dv * p.w);
    atomicAdd(&lac[g + 4], idg);
    atomicAdd(&lac[g + 5], 1.0f);
  }
  __syncthreads();
  for (int t = threadIdx.x; t < NGRAPH; t += blockDim.x) {
    gAtomicAdd(&U[t * 4 + 0], lac[t * 7 + 0]);
    gAtomicAdd(&U[t * 4 + 1], lac[t * 7 + 1]);
    gAtomicAdd(&U[t * 4 + 2], lac[t * 7 + 2]);
    gAtomicAdd(&U[t * 4 + 3], lac[t * 7 + 3]);
    gAtomicAdd(&S[t], lac[t * 7 + 4]);
    gAtomicAdd(&cnt[t], lac[t * 7 + 5]);
  }
}

// ---------- edge pass B: per-graph U += dinv[d]*p2[src], S += w -----------
__global__ void k_edgeB(const int* __restrict__ ei, int E,
                        const float4* __restrict__ p2,
                        const float* __restrict__ dinv,
                        const int* __restrict__ batch, float* __restrict__ U,
                        float* __restrict__ S) {
  __shared__ float lac[4 * NGRAPH * 5];  // per-wave replicas
  for (int t = threadIdx.x; t < 4 * NGRAPH * 5; t += blockDim.x) lac[t] = 0.f;
  __syncthreads();
  float* wl = lac + (threadIdx.x >> 6) * (NGRAPH * 5);
  for (int e = blockIdx.x * blockDim.x + threadIdx.x; e < E;
       e += gridDim.x * blockDim.x) {
    int s = ei[e];
    int d = ei[E + e];
    float dvd = dinv[d];
    int g = batch[d] * 5;
    float4 p = p2[s];
    atomicAdd(&wl[g + 0], dvd * p.x);
    atomicAdd(&wl[g + 1], dvd * p.y);
    atomicAdd(&wl[g + 2], dvd * p.z);
    atomicAdd(&wl[g + 3], dvd * p.w);
    atomicAdd(&wl[g + 4], dvd * dinv[s]);
  }
  __syncthreads();
  for (int t = threadIdx.x; t < NGRAPH; t += blockDim.x) {
    float u0 = 0, u1 = 0, u2 = 0, u3 = 0, ws = 0;
#pragma unroll
    for (int w = 0; w < 4; w++) {
      const float* b = lac + w * (NGRAPH * 5) + t * 5;
      u0 += b[0]; u1 += b[1]; u2 += b[2]; u3 += b[3]; ws += b[4];
    }
    gAtomicAdd(&U[t * 4 + 0], u0);
    gAtomicAdd(&U[t * 4 + 1], u1);
    gAtomicAdd(&U[t * 4 + 2], u2);
    gAtomicAdd(&U[t * 4 + 3], u3);
    gAtomicAdd(&S[t], ws);
  }
}

// ---------- epilogue: g_raw = U@(W0W1)+S*(b0W1)+cnt*b1 -> BN -> MLP --------
__global__ void k_final(const float* __restrict__ U, const float* __restrict__ S,
                        const float* __restrict__ cnt,
                        const float* __restrict__ W0, const float* __restrict__ b0,
                        const float* __restrict__ W1, const float* __restrict__ b1,
                        const float* __restrict__ bn1g,
                        const float* __restrict__ bn1b,
                        const float* __restrict__ l0W, const float* __restrict__ l0b,
                        const float* __restrict__ l1W, const float* __restrict__ l1b,
                        const float* __restrict__ oW, const float* __restrict__ ob,
                        float* __restrict__ out) {
  __shared__ float sW01[4 * 64];
  __shared__ float sb01[64];
  __shared__ float sA[64 * 64];
  __shared__ float sB[64 * 64];
  __shared__ float sSc[64], sSh[64];
  int t = threadIdx.x;
  {
    int k = t >> 6, f = t & 63;
    float a = 0.f;
    for (int j = 0; j < 64; j++) a += W0[k * 64 + j] * W1[j * 64 + f];
    sW01[k * 64 + f] = a;
  }
  if (t < 64) {
    float a = 0.f;
    for (int j = 0; j < 64; j++) a += b0[j] * W1[j * 64 + t];
    sb01[t] = a;
  }
  __syncthreads();
  for (int idx = t; idx < 4096; idx += 256) {
    int G = idx >> 6, f = idx & 63;
    float v = cnt[G] * b1[f] + S[G] * sb01[f];
    v += U[G * 4 + 0] * sW01[0 * 64 + f];
    v += U[G * 4 + 1] * sW01[1 * 64 + f];
    v += U[G * 4 + 2] * sW01[2 * 64 + f];
    v += U[G * 4 + 3] * sW01[3 * 64 + f];
    sA[idx] = v;
  }
  __syncthreads();
  if (t < 64) {
    float mu = 0.f;
    for (int G = 0; G < 64; G++) mu += sA[G * 64 + t];
    mu *= (1.0f / 64.0f);
    float var = 0.f;
    for (int G = 0; G < 64; G++) {
      float d = sA[G * 64 + t] - mu;
      var += d * d;
    }
    var *= (1.0f / 64.0f);
    float s = bn1g[t] / sqrtf(var + EPSF);
    sSc[t] = s;
    sSh[t] = bn1b[t] - mu * s;
  }
  __syncthreads();
  for (int idx = t; idx < 4096; idx += 256) {
    int f = idx & 63;
    sA[idx] = sA[idx] * sSc[f] + sSh[f];
  }
  __syncthreads();
  for (int idx = t; idx < 4096; idx += 256) {
    int G = idx >> 6, f = idx & 63;
    float v = l0b[f];
    for (int j = 0; j < 64; j++) v += sA[G * 64 + j] * l0W[j * 64 + f];
    sB[idx] = v;
  }
  __syncthreads();
  for (int idx = t; idx < 4096; idx += 256) {
    int G = idx >> 6, f = idx & 63;
    float v = l1b[f];
    for (int j = 0; j < 64; j++) v += sB[G * 64 + j] * l1W[j * 64 + f];
    sA[idx] = v;
  }
  __syncthreads();
  if (t < 64) {
    float v = ob[0];
    for (int j = 0; j < 64; j++) v += sA[t * 64 + j] * oW[j];
    out[t] = v;
  }
}

extern "C" void kernel_launch(void* const* d_in, const int* in_sizes, int n_in,
                              void* d_out, int out_size, void* d_ws,
                              size_t ws_size, hipStream_t stream) {
  const float* x = (const float*)d_in[0];
  const int* ei = (const int*)d_in[1];
  const int* batch = (const int*)d_in[2];
  const float* bn0g = (const float*)d_in[3];
  const float* bn0b = (const float*)d_in[4];
  const float* W0 = (const float*)d_in[5];
  const float* b0 = (const float*)d_in[6];
  const float* W1 = (const float*)d_in[7];
  const float* b1 = (const float*)d_in[8];
  const float* bn1g = (const float*)d_in[9];
  const float* bn1b = (const float*)d_in[10];
  const float* l0W = (const float*)d_in[11];
  const float* l0b = (const float*)d_in[12];
  const float* l1W = (const float*)d_in[13];
  const float* l1b = (const float*)d_in[14];
  const float* oW = (const float*)d_in[15];
  const float* ob = (const float*)d_in[16];

  const int N = in_sizes[0] / 4;
  const int E = in_sizes[1] / 2;
  const int R = (N + HB - 1) / HB;
  const int chunk = (E + CHK - 1) / CHK;

  size_t off = 0;
  auto alloc = [&](size_t nbytes) {
    size_t cur = (off + 15) & ~(size_t)15;
    off = cur + nbytes;
    return (void*)((char*)d_ws + cur);
  };
  // --- zeroed region first ---
  unsigned long long* acc = (unsigned long long*)alloc((size_t)N * 16);
  float* stats = (float*)alloc(8 * 4);
  float* U = (float*)alloc(NGRAPH * 4 * 4);
  float* S = (float*)alloc(NGRAPH * 4);
  float* cnt = (float*)alloc(NGRAPH * 4);
  unsigned* degcnt = (unsigned*)alloc((size_t)N * 4);  // zeroed (fallback path)
  const size_t zero_bytes = off;
  // --- non-zeroed ---
  float* dinv = (float*)alloc((size_t)N * 4);
  uint4* qz = (uint4*)alloc((size_t)N * 16);
  float4* p2 = (float4*)alloc((size_t)N * 16);
  unsigned* part = (unsigned*)alloc((size_t)CHK * R * HB * 4);
  const bool use_hist = (off <= ws_size);

  hipMemsetAsync(d_ws, 0, zero_bytes, stream);

  const float Ninv = 1.0f / (float)N;
  k_bnstats<<<256, 256, 0, stream>>>((const float4*)x, N, stats);
  if (use_hist) {
    k_hist<<<CHK * R, 256, 0, stream>>>(ei, E, R, chunk, part);
    k_degreduce<<<(N + 255) / 256, 256, 0, stream>>>(part, N, R, degcnt);
  } else {
    k_degatomic<<<1024, 256, 0, stream>>>(ei, E, degcnt);
  }
  k_prep<<<(N + 255) / 256, 256, 0, stream>>>((const float4*)x, degcnt, N,
                                              stats, bn0g, bn0b, Ninv, dinv,
                                              qz);
  k_edgeA<<<2048, 256, 0, stream>>>(ei, E, qz, acc);
  k_pre1<<<(N + 255) / 256, 256, 0, stream>>>(
      (const float4*)x, (const ulonglong2*)acc, degcnt, dinv, batch, N, stats,
      bn0g, bn0b, Ninv, p2, U, S, cnt);
  k_edgeB<<<512, 256, 0, stream>>>(ei, E, p2, dinv, batch, U, S);
  k_final<<<1, 256, 0, stream>>>(U, S, cnt, W0, b0, W1, b1, bn1g, bn1b, l0W,
                                 l0b, l1W, l1b, oW, ob, (float*)d_out);
}